// Round 2
// baseline (380.423 us; speedup 1.0000x reference)
//
#include <hip/hip_runtime.h>

namespace {

constexpr int NS     = 51;
constexpr int NSP    = 52;   // padded row stride (col 51 is zero padding)
constexpr int NITERS = 50;

// constexpr double-precision exp (range-reduce + Taylor), accurate far beyond f32
constexpr double cexp_d(double x) {
  const double LN2 = 0.6931471805599453094172321214582;
  const double t = x / LN2;
  const int k = (int)(t >= 0.0 ? t + 0.5 : t - 0.5);
  const double r = x - (double)k * LN2;
  double term = 1.0, sum = 1.0;
  for (int i = 1; i <= 30; ++i) { term *= r / (double)i; sum += term; }
  double p = 1.0;
  if (k >= 0) { for (int i = 0; i < k;  ++i) p *= 2.0; }
  else        { for (int i = 0; i < -k; ++i) p *= 0.5; }
  return sum * p;
}

struct Tbl { float v[NS * NSP]; };

// SSS[i][j] = exp(-f32(DELTAW[i][j]) / f32(RGAS*T)); DELTAW computed in double
// like the numpy reference. SSS is symmetric (sigma_acc[i,j]=s[max], sigma_don=s[min]).
constexpr Tbl make_tbl() {
  Tbl T{};
  double sq = 2.7;                       // sqrt(7.5) by Newton
  for (int i = 0; i < 50; ++i) sq = 0.5 * (sq + 7.5 / sq);
  const double alpha = 0.3 * (7.5 * sq) / 0.0002395;   // 0.3*AEFF^1.5/EO
  const double fpol  = (3.667 - 1.0) / (3.667 + 0.5);
  const double ap    = fpol * alpha;                   // alpha_prime
  const double RGAST = (8.3144598 / 4184.0) * 623.15;
  const float  rgast_f = (float)RGAST;
  for (int i = 0; i < NS; ++i) {
    for (int j = 0; j < NS; ++j) {
      const double si = -0.025 + 0.001 * (double)i;
      const double sj = -0.025 + 0.001 * (double)j;
      const double smax = si > sj ? si : sj;
      const double smin = si < sj ? si : sj;
      double acc = smax - 0.0084; if (acc < 0.0) acc = 0.0;   // max(0, sigma_acc - SIG_HB)
      double don = smin + 0.0084; if (don > 0.0) don = 0.0;   // min(0, sigma_don + SIG_HB)
      const double dw = ap * 0.5 * (si + sj) * (si + sj) + 85580.0 * acc * don;
      const float dwf = (float)dw;
      const float arg = -(dwf / rgast_f);
      T.v[i * NSP + j] = (float)cexp_d((double)arg);
    }
    T.v[i * NSP + NS] = 0.0f;            // padding column (unused after 3-wide tail)
  }
  return T;
}

constexpr Tbl TBL = make_tbl();

__device__ __forceinline__ float fast_log(float x) {
  // x > 0 guaranteed (Gamma and psigma ratios are positive)
  return __builtin_amdgcn_logf(x) * 0.69314718056f;
}

} // namespace

// One lane per (element, task): even lane = pure solve, odd lane = mix solve.
// Hot loop is lane-uniform (same SSS literals for all lanes) -> no divergence.
// __launch_bounds__(256,1): 1 wave/EU min -> VGPR cap 512; w/G/H (153 floats)
// must stay in registers. R1 showed default heuristic capped at 104 -> scratch.
__global__ __launch_bounds__(256, 1) void cosmo_kernel(
    const float* __restrict__ my_sigma,   // [B,51]
    const float* __restrict__ v_comp,     // [B]
    const float* __restrict__ vt_sigma,   // [B,51,2]
    const float* __restrict__ v_vt,       // [B]
    float* __restrict__ out,              // [B]
    int B)
{
  const int t = blockIdx.x * 256 + threadIdx.x;
  const int e = t >> 1;
  if (e >= B) return;
  const int task = t & 1;

  const float* __restrict__ myp = my_sigma + (size_t)e * NS;
  const float* __restrict__ vtp = vt_sigma + (size_t)e * NS * 2;

  float w[NS];
  float A0 = 0.f, A1 = 0.f;
#pragma unroll
  for (int n = 0; n < NS; ++n) {
    const float a = myp[n];
    const float b = vtp[2 * n + 1];
    A0 += a;
    A1 += b;
    w[n] = task ? (0.235f * a + 0.765f * b) : a;
  }
  const float den  = task ? (0.235f * A0 + 0.765f * A1) : A0;
  const float rden = __builtin_amdgcn_rcpf(den);
#pragma unroll
  for (int n = 0; n < NS; ++n) w[n] *= rden;

  float G[NS];
#pragma unroll
  for (int n = 0; n < NS; ++n) G[n] = 1.0f;

  // 50-step damped fixed point: G <- 0.5*(G + 1/(SSS @ (w*G)))
#pragma unroll 1
  for (int it = 0; it < NITERS; ++it) {
    float H[NS];
#pragma unroll
    for (int n = 0; n < NS; ++n) H[n] = w[n] * G[n];

    // m unrolled x4 (12 groups) + 3-wide tail: independent FMA chains
    // (8-cyc reissue spacing > 4-cyc FMA latency). TBL reads constant-fold
    // to FMA literals (TBL is constexpr) -> zero memory ops in hot loop.
#pragma unroll
    for (int m0 = 0; m0 < 48; m0 += 4) {
      float d0 = 0.f, d1 = 0.f, d2 = 0.f, d3 = 0.f;
#pragma unroll
      for (int n = 0; n < NS; ++n) {
        const float h = H[n];
        d0 += TBL.v[n * NSP + m0 + 0] * h;   // SSS[m][n] via symmetry
        d1 += TBL.v[n * NSP + m0 + 1] * h;
        d2 += TBL.v[n * NSP + m0 + 2] * h;
        d3 += TBL.v[n * NSP + m0 + 3] * h;
      }
      G[m0 + 0] = 0.5f * (G[m0 + 0] + __builtin_amdgcn_rcpf(d0));
      G[m0 + 1] = 0.5f * (G[m0 + 1] + __builtin_amdgcn_rcpf(d1));
      G[m0 + 2] = 0.5f * (G[m0 + 2] + __builtin_amdgcn_rcpf(d2));
      G[m0 + 3] = 0.5f * (G[m0 + 3] + __builtin_amdgcn_rcpf(d3));
    }
    {
      float d0 = 0.f, d1 = 0.f, d2 = 0.f;
#pragma unroll
      for (int n = 0; n < NS; ++n) {
        const float h = H[n];
        d0 += TBL.v[n * NSP + 48] * h;
        d1 += TBL.v[n * NSP + 49] * h;
        d2 += TBL.v[n * NSP + 50] * h;
      }
      G[48] = 0.5f * (G[48] + __builtin_amdgcn_rcpf(d0));
      G[49] = 0.5f * (G[49] + __builtin_amdgcn_rcpf(d1));
      G[50] = 0.5f * (G[50] + __builtin_amdgcn_rcpf(d2));
    }
  }

  // S = sum_n psigma_pure[n] * ln(Gamma[n])  (weights are ALWAYS the pure psigma)
  const float rA0 = __builtin_amdgcn_rcpf(A0);
  float S = 0.f;
#pragma unroll
  for (int n = 0; n < NS; ++n) {
    const float p = myp[n] * rA0;
    S += p * fast_log(G[n]);
  }

  // lane pair (2e, 2e+1) exchange: even lane holds S_pure, gets S_mix
  const float So = __shfl_xor(S, 1, 64);

  if (task == 0) {
    const float lng_resid = A0 * (1.0f / 7.5f) * (So - S);
    const float v0  = v_comp[e];
    const float v1v = v_vt[e];
    const float q0 = A0 * (1.0f / 79.53f), q1 = A1 * (1.0f / 79.53f);
    const float r0 = v0 * (1.0f / 66.69f), r1 = v1v * (1.0f / 66.69f);
    const float xq = 0.235f * q0 + 0.765f * q1;
    const float xr = 0.235f * r0 + 0.765f * r1;
    const float theta = 0.235f * q0 * __builtin_amdgcn_rcpf(xq);
    const float phi   = 0.235f * r0 * __builtin_amdgcn_rcpf(xr);
    const float l0 = 5.0f * (r0 - q0) - (r0 - 1.0f);
    const float l1 = 5.0f * (r1 - q1) - (r1 - 1.0f);
    const float xl = 0.235f * l0 + 0.765f * l1;
    const float lng_comb = fast_log(phi * (1.0f / 0.235f))
                         + 5.0f * q0 * fast_log(theta * __builtin_amdgcn_rcpf(phi))
                         + l0 - (phi * (1.0f / 0.235f)) * xl;
    out[e] = lng_resid + lng_comb;
  }
}

extern "C" void kernel_launch(void* const* d_in, const int* in_sizes, int n_in,
                              void* d_out, int out_size, void* d_ws, size_t ws_size,
                              hipStream_t stream) {
  const float* my  = (const float*)d_in[0];
  const float* vc  = (const float*)d_in[1];
  const float* vts = (const float*)d_in[2];
  const float* vvt = (const float*)d_in[3];
  float* out = (float*)d_out;
  const int B = in_sizes[1];          // v_compound is [B]
  const int threads = 2 * B;
  const int block = 256;
  const int grid = (threads + block - 1) / block;
  cosmo_kernel<<<grid, block, 0, stream>>>(my, vc, vts, vvt, out, B);
}

// Round 3
// 339.614 us; speedup vs baseline: 1.1202x; 1.1202x over previous
//
#include <hip/hip_runtime.h>

namespace {

constexpr int NS     = 51;
constexpr int NSP    = 52;   // padded row stride in the constant table
constexpr int NITERS = 50;

// constexpr double-precision exp (range-reduce + Taylor), accurate far beyond f32
constexpr double cexp_d(double x) {
  const double LN2 = 0.6931471805599453094172321214582;
  const double t = x / LN2;
  const int k = (int)(t >= 0.0 ? t + 0.5 : t - 0.5);
  const double r = x - (double)k * LN2;
  double term = 1.0, sum = 1.0;
  for (int i = 1; i <= 30; ++i) { term *= r / (double)i; sum += term; }
  double p = 1.0;
  if (k >= 0) { for (int i = 0; i < k;  ++i) p *= 2.0; }
  else        { for (int i = 0; i < -k; ++i) p *= 0.5; }
  return sum * p;
}

struct Tbl { float v[NS * NSP]; };

// SSS[i][j] = exp(-f32(DELTAW[i][j]) / f32(RGAS*T)); DELTAW computed in double
// like the numpy reference. SSS is symmetric (sigma_acc[i,j]=s[max], sigma_don=s[min]).
constexpr Tbl make_tbl() {
  Tbl T{};
  double sq = 2.7;                       // sqrt(7.5) by Newton
  for (int i = 0; i < 50; ++i) sq = 0.5 * (sq + 7.5 / sq);
  const double alpha = 0.3 * (7.5 * sq) / 0.0002395;   // 0.3*AEFF^1.5/EO
  const double fpol  = (3.667 - 1.0) / (3.667 + 0.5);
  const double ap    = fpol * alpha;                   // alpha_prime
  const double RGAST = (8.3144598 / 4184.0) * 623.15;
  const float  rgast_f = (float)RGAST;
  for (int i = 0; i < NS; ++i) {
    for (int j = 0; j < NS; ++j) {
      const double si = -0.025 + 0.001 * (double)i;
      const double sj = -0.025 + 0.001 * (double)j;
      const double smax = si > sj ? si : sj;
      const double smin = si < sj ? si : sj;
      double acc = smax - 0.0084; if (acc < 0.0) acc = 0.0;   // max(0, sigma_acc - SIG_HB)
      double don = smin + 0.0084; if (don > 0.0) don = 0.0;   // min(0, sigma_don + SIG_HB)
      const double dw = ap * 0.5 * (si + sj) * (si + sj) + 85580.0 * acc * don;
      const float dwf = (float)dw;
      const float arg = -(dwf / rgast_f);
      T.v[i * NSP + j] = (float)cexp_d((double)arg);
    }
    T.v[i * NSP + NS] = 0.0f;
  }
  return T;
}

constexpr Tbl TBL = make_tbl();

__device__ __forceinline__ float fast_log(float x) {
  // x > 0 guaranteed (Gamma and psigma ratios are positive)
  return __builtin_amdgcn_logf(x) * 0.69314718056f;
}

// ---------- template-expanded pieces: EVERY array index is constexpr ----------
// (R1/R2 showed #pragma unroll was not honored for the 13x51 nest: VGPR=104 and
//  2.3x excess VALU issue => G was scratch-resident. Templates force SROA.)

template<int N>
__device__ __forceinline__ void prolog(const float* __restrict__ myp,
                                       const float* __restrict__ vtp,
                                       float* __restrict__ w,
                                       float& A0, float& A1, int task) {
  if constexpr (N < NS) {
    const float a = myp[N];
    const float b = vtp[2 * N + 1];
    A0 += a;
    A1 += b;
    w[N] = task ? (0.235f * a + 0.765f * b) : a;
    prolog<N + 1>(myp, vtp, w, A0, A1, task);
  }
}

template<int N>
__device__ __forceinline__ void scale_w(float* __restrict__ w, float rden) {
  if constexpr (N < NS) { w[N] *= rden; scale_w<N + 1>(w, rden); }
}

template<int N>
__device__ __forceinline__ void init_g(float* __restrict__ G) {
  if constexpr (N < NS) { G[N] = 1.0f; init_g<N + 1>(G); }
}

template<int N>
__device__ __forceinline__ void build_h(float* __restrict__ H,
                                        const float* __restrict__ w,
                                        const float* __restrict__ G) {
  if constexpr (N < NS) { H[N] = w[N] * G[N]; build_h<N + 1>(H, w, G); }
}

// W independent fmac chains (W=4 main, W=3 tail); literal table operand folds
// into v_fmac_f32 (VOP2 literal-src0, dst==addend).
template<int M0, int W, int N>
__device__ __forceinline__ void dot_n(const float* __restrict__ H,
                                      float* __restrict__ d) {
  if constexpr (N < NS) {
    const float h = H[N];
    d[0] = __builtin_fmaf(TBL.v[N * NSP + M0 + 0], h, d[0]);
    if constexpr (W > 1) d[1] = __builtin_fmaf(TBL.v[N * NSP + M0 + 1], h, d[1]);
    if constexpr (W > 2) d[2] = __builtin_fmaf(TBL.v[N * NSP + M0 + 2], h, d[2]);
    if constexpr (W > 3) d[3] = __builtin_fmaf(TBL.v[N * NSP + M0 + 3], h, d[3]);
    dot_n<M0, W, N + 1>(H, d);
  }
}

template<int M0, int W>
__device__ __forceinline__ void group(float* __restrict__ G,
                                      const float* __restrict__ H) {
  float d[W] = {};
  dot_n<M0, W, 0>(H, d);
  G[M0 + 0] = 0.5f * (G[M0 + 0] + __builtin_amdgcn_rcpf(d[0]));
  if constexpr (W > 1) G[M0 + 1] = 0.5f * (G[M0 + 1] + __builtin_amdgcn_rcpf(d[1]));
  if constexpr (W > 2) G[M0 + 2] = 0.5f * (G[M0 + 2] + __builtin_amdgcn_rcpf(d[2]));
  if constexpr (W > 3) G[M0 + 3] = 0.5f * (G[M0 + 3] + __builtin_amdgcn_rcpf(d[3]));
}

template<int M0>
__device__ __forceinline__ void all_groups(float* __restrict__ G,
                                           const float* __restrict__ H) {
  if constexpr (M0 + 4 <= NS - 3) {        // groups 0..44 (12 x width-4)
    group<M0, 4>(G, H);
    all_groups<M0 + 4>(G, H);
  } else {                                  // tail m=48,49,50 (width-3)
    group<M0, 3>(G, H);
  }
}

template<int N>
__device__ __forceinline__ void epilog_sum(const float* __restrict__ myp,
                                           const float* __restrict__ G,
                                           float rA0, float& S) {
  if constexpr (N < NS) {
    S += (myp[N] * rA0) * fast_log(G[N]);
    epilog_sum<N + 1>(myp, G, rA0, S);
  }
}

} // namespace

// One lane per (element, task): even lane = pure solve, odd lane = mix solve.
// Hot loop is lane-uniform (same SSS literals for all lanes) -> no divergence.
__global__ __launch_bounds__(256, 1) void cosmo_kernel(
    const float* __restrict__ my_sigma,   // [B,51]
    const float* __restrict__ v_comp,     // [B]
    const float* __restrict__ vt_sigma,   // [B,51,2]
    const float* __restrict__ v_vt,       // [B]
    float* __restrict__ out,              // [B]
    int B)
{
  const int t = blockIdx.x * 256 + threadIdx.x;
  const int e = t >> 1;
  if (e >= B) return;
  const int task = t & 1;

  const float* __restrict__ myp = my_sigma + (size_t)e * NS;
  const float* __restrict__ vtp = vt_sigma + (size_t)e * NS * 2;

  float w[NS];
  float A0 = 0.f, A1 = 0.f;
  prolog<0>(myp, vtp, w, A0, A1, task);

  const float den  = task ? (0.235f * A0 + 0.765f * A1) : A0;
  const float rden = __builtin_amdgcn_rcpf(den);
  scale_w<0>(w, rden);

  float G[NS];
  init_g<0>(G);

  // 50-step damped fixed point: G <- 0.5*(G + 1/(SSS @ (w*G)))
#pragma unroll 1
  for (int it = 0; it < NITERS; ++it) {
    float H[NS];
    build_h<0>(H, w, G);
    all_groups<0>(G, H);
  }

  // S = sum_n psigma_pure[n] * ln(Gamma[n])  (weights are ALWAYS the pure psigma)
  const float rA0 = __builtin_amdgcn_rcpf(A0);
  float S = 0.f;
  epilog_sum<0>(myp, G, rA0, S);

  // lane pair (2e, 2e+1) exchange: even lane holds S_pure, gets S_mix
  const float So = __shfl_xor(S, 1, 64);

  if (task == 0) {
    const float lng_resid = A0 * (1.0f / 7.5f) * (So - S);
    const float v0  = v_comp[e];
    const float v1v = v_vt[e];
    const float q0 = A0 * (1.0f / 79.53f), q1 = A1 * (1.0f / 79.53f);
    const float r0 = v0 * (1.0f / 66.69f), r1 = v1v * (1.0f / 66.69f);
    const float xq = 0.235f * q0 + 0.765f * q1;
    const float xr = 0.235f * r0 + 0.765f * r1;
    const float theta = 0.235f * q0 * __builtin_amdgcn_rcpf(xq);
    const float phi   = 0.235f * r0 * __builtin_amdgcn_rcpf(xr);
    const float l0 = 5.0f * (r0 - q0) - (r0 - 1.0f);
    const float l1 = 5.0f * (r1 - q1) - (r1 - 1.0f);
    const float xl = 0.235f * l0 + 0.765f * l1;
    const float lng_comb = fast_log(phi * (1.0f / 0.235f))
                         + 5.0f * q0 * fast_log(theta * __builtin_amdgcn_rcpf(phi))
                         + l0 - (phi * (1.0f / 0.235f)) * xl;
    out[e] = lng_resid + lng_comb;
  }
}

extern "C" void kernel_launch(void* const* d_in, const int* in_sizes, int n_in,
                              void* d_out, int out_size, void* d_ws, size_t ws_size,
                              hipStream_t stream) {
  const float* my  = (const float*)d_in[0];
  const float* vc  = (const float*)d_in[1];
  const float* vts = (const float*)d_in[2];
  const float* vvt = (const float*)d_in[3];
  float* out = (float*)d_out;
  const int B = in_sizes[1];          // v_compound is [B]
  const int threads = 2 * B;
  const int block = 256;
  const int grid = (threads + block - 1) / block;
  cosmo_kernel<<<grid, block, 0, stream>>>(my, vc, vts, vvt, out, B);
}

// Round 4
// 117.941 us; speedup vs baseline: 3.2255x; 2.8795x over previous
//
#include <hip/hip_runtime.h>

typedef __bf16 bf16;
typedef __attribute__((ext_vector_type(4))) bf16 bf16x4;
typedef __attribute__((ext_vector_type(8))) bf16 bf16x8;
typedef __attribute__((ext_vector_type(16))) float f32x16;

namespace {

// ---- compile-time physical constants (double) ----
constexpr double csqrt(double x) {
  double s = x > 1 ? x : 1;
  for (int i = 0; i < 60; ++i) s = 0.5 * (s + x / s);
  return s;
}
constexpr double AP_D =
    ((3.667 - 1.0) / (3.667 + 0.5)) * (0.3 * (7.5 * csqrt(7.5)) / 0.0002395);
constexpr double RGAST_D = (8.3144598 / 4184.0) * 623.15;

__device__ __forceinline__ float sss_val(int i, int j) {
  // SSS[i][j] = exp(-DELTAW/(RGAS*T)); symmetric; zero outside 51x51 (pad)
  if (i > 50 || j > 50) return 0.0f;
  const float si = -0.025f + 0.001f * (float)i;
  const float sj = -0.025f + 0.001f * (float)j;
  const float smx = fmaxf(si, sj);
  const float smn = fminf(si, sj);
  const float acc = fmaxf(0.0f, smx - 0.0084f);
  const float don = fminf(0.0f, smn + 0.0084f);
  const float dw = (float)(AP_D * 0.5) * (si + sj) * (si + sj) + 85580.0f * acc * don;
  return expf(-dw * (float)(1.0 / RGAST_D));
}

__device__ __forceinline__ float fast_log(float x) {
  return __builtin_amdgcn_logf(x) * 0.69314718056f;   // ln via log2
}

__device__ __forceinline__ f32x16 mfma_bf16(bf16x8 a, bf16x8 b, f32x16 c) {
  return __builtin_amdgcn_mfma_f32_32x32x16_bf16(a, b, c, 0, 0, 0);
}

} // namespace

// One wave = 32 solves (16 elements x {pure, mix}). Per iteration:
//   D[n_out, s] = Sigma_k S[n_out,k] * H[k,s]   via 2 m-tiles x 4 k-tiles of
//   v_mfma_f32_32x32x16_bf16 (A = S, constant bf16 frags; B = H from LDS).
// C/D layout: col = lane&31 = solve s, row = (reg&3)+8*(reg>>2)+4*(lane>>5).
// Elementwise (rcp, damped avg, H=w*G) stays in C-layout; H goes C->B-operand
// via a wave-private LDS slice ([s][n], stride 68 bf16 -> 2-way banks = free).
// Pads: S rows/cols >=51 are 0; invalid rows get d+=1 so G==1 (finite, ln=0);
// w==0 on n>=51 keeps H==0. No __syncthreads needed (wave-private LDS, DS in-order).
__global__ __launch_bounds__(256, 1) void cosmo_mfma(
    const float* __restrict__ my_sigma,   // [B,51]
    const float* __restrict__ v_comp,     // [B]
    const float* __restrict__ vt_sigma,   // [B,51,2]
    const float* __restrict__ v_vt,       // [B]
    float* __restrict__ out,              // [B]
    int B)
{
  __shared__ bf16 lds[4][32 * 68];

  const int lane = threadIdx.x & 63;
  const int wv   = threadIdx.x >> 6;
  const int s    = lane & 31;     // solve slot within wave
  const int hf   = lane >> 5;     // lane half
  const int e    = (blockIdx.x * 4 + wv) * 16 + (s >> 1);
  const int task = s & 1;         // 0 = pure, 1 = mix
  const bool ein = (e < B);
  const int  ec  = ein ? e : 0;

  // ---- load inputs into C-layout slots: n(t,r) = 32t + (r&3) + 8(r>>2) + 4hf ----
  float myv[2][16], vtv[2][16];
#pragma unroll
  for (int t = 0; t < 2; ++t)
#pragma unroll
    for (int r = 0; r < 16; ++r) {
      const int n  = 32 * t + (r & 3) + 8 * (r >> 2) + 4 * hf;
      const bool nv = (n < 51);
      const int nc = nv ? n : 50;
      const float a = my_sigma[(size_t)ec * 51 + nc];
      const float b = vt_sigma[((size_t)ec * 51 + nc) * 2 + 1];
      myv[t][r] = nv ? a : 0.0f;
      vtv[t][r] = nv ? b : 0.0f;
    }

  float pA0 = 0.f, pA1 = 0.f;
#pragma unroll
  for (int t = 0; t < 2; ++t)
#pragma unroll
    for (int r = 0; r < 16; ++r) { pA0 += myv[t][r]; pA1 += vtv[t][r]; }
  const float A0 = pA0 + __shfl_xor(pA0, 32, 64);
  const float A1 = pA1 + __shfl_xor(pA1, 32, 64);

  const float den  = task ? (0.235f * A0 + 0.765f * A1) : A0;
  const float rden = __builtin_amdgcn_rcpf(den);
  const float rA0  = __builtin_amdgcn_rcpf(A0);

  float wC[2][16], pp[2][16], G[2][16];
#pragma unroll
  for (int t = 0; t < 2; ++t)
#pragma unroll
    for (int r = 0; r < 16; ++r) {
      const float num = task ? (0.235f * myv[t][r] + 0.765f * vtv[t][r]) : myv[t][r];
      wC[t][r] = num * rden;                       // psigma of this task; 0 on pads
      pp[t][r] = myv[t][r] * rA0 * 0.69314718f;    // pure psigma, pre-scaled by ln2
      G[t][r]  = 1.0f;
    }

  // ---- constant A fragments: A[t][kt] lane holds S[32t+s][kt*16 + 8hf + i] ----
  bf16x8 afr[2][4];
#pragma unroll
  for (int t = 0; t < 2; ++t)
#pragma unroll
    for (int kt = 0; kt < 4; ++kt) {
      bf16x8 v;
#pragma unroll
      for (int i = 0; i < 8; ++i)
        v[i] = (bf16)sss_val(32 * t + s, kt * 16 + 8 * hf + i);
      afr[t][kt] = v;
    }

  bf16* slab = &lds[wv][0];
  const int wbase = s * 68 + 4 * hf;   // + 32t + 8q  (writes: quad of consecutive n)
  const int rbase = s * 68 + 8 * hf;   // + 16*kt     (reads: 8 consecutive k)
  const float vInd = hf ? 1.0f : 0.0f; // tile-1 q==2 validity depends on lane half

  // ---- 50-step damped fixed point ----
#pragma unroll 1
  for (int it = 0; it < 50; ++it) {
    // H = w*G -> bf16 -> LDS (8 x ds_write_b64, 2-way banks = free)
#pragma unroll
    for (int t = 0; t < 2; ++t)
#pragma unroll
      for (int q = 0; q < 4; ++q) {
        bf16x4 hv;
#pragma unroll
        for (int r = 0; r < 4; ++r)
          hv[r] = (bf16)(wC[t][q * 4 + r] * G[t][q * 4 + r]);
        *(bf16x4*)(slab + wbase + 32 * t + 8 * q) = hv;
      }

    // B fragments: H[k = kt*16 + 8hf + i][s]
    bf16x8 bfr[4];
#pragma unroll
    for (int kt = 0; kt < 4; ++kt) {
      const bf16x4 lo = *(const bf16x4*)(slab + rbase + 16 * kt);
      const bf16x4 hi = *(const bf16x4*)(slab + rbase + 16 * kt + 4);
      bfr[kt] = __builtin_shufflevector(lo, hi, 0, 1, 2, 3, 4, 5, 6, 7);
    }

    const f32x16 z = {};
    f32x16 acc0 = mfma_bf16(afr[0][0], bfr[0], z);
    f32x16 acc1 = mfma_bf16(afr[1][0], bfr[0], z);
#pragma unroll
    for (int kt = 1; kt < 4; ++kt) {
      acc0 = mfma_bf16(afr[0][kt], bfr[kt], acc0);
      acc1 = mfma_bf16(afr[1][kt], bfr[kt], acc1);
    }

    // G <- 0.5*(G + 1/d); tile-1 invalid rows (n_out>=51) get d+=1 -> G stays 1
#pragma unroll
    for (int r = 0; r < 16; ++r)
      G[0][r] = 0.5f * (G[0][r] + __builtin_amdgcn_rcpf(acc0[r]));
#pragma unroll
    for (int r = 0; r < 16; ++r) {
      float d = acc1[r];
      const int q = r >> 2;
      if (q == 3)      d += 1.0f;
      else if (q == 2) d += ((r & 3) == 3) ? 1.0f : vInd;
      G[1][r] = 0.5f * (G[1][r] + __builtin_amdgcn_rcpf(d));
    }
  }

  // ---- epilogue: S_task = sum_n psigma_pure[n] * ln(G[n]) ----
  float Sp = 0.f;
#pragma unroll
  for (int t = 0; t < 2; ++t)
#pragma unroll
    for (int r = 0; r < 16; ++r)
      Sp += pp[t][r] * __builtin_amdgcn_logf(G[t][r]);   // pp pre-scaled by ln2

  const float St = Sp + __shfl_xor(Sp, 32, 64);  // full 51-sum (both halves)
  const float So = __shfl_xor(St, 1, 64);        // the other task's sum

  if (task == 0 && hf == 0 && ein) {
    const float lng_resid = A0 * (1.0f / 7.5f) * (So - St);
    const float v0  = v_comp[e];
    const float v1v = v_vt[e];
    const float q0 = A0 * (1.0f / 79.53f), q1 = A1 * (1.0f / 79.53f);
    const float r0 = v0 * (1.0f / 66.69f), r1 = v1v * (1.0f / 66.69f);
    const float xq = 0.235f * q0 + 0.765f * q1;
    const float xr = 0.235f * r0 + 0.765f * r1;
    const float theta = 0.235f * q0 * __builtin_amdgcn_rcpf(xq);
    const float phi   = 0.235f * r0 * __builtin_amdgcn_rcpf(xr);
    const float l0 = 5.0f * (r0 - q0) - (r0 - 1.0f);
    const float l1 = 5.0f * (r1 - q1) - (r1 - 1.0f);
    const float xl = 0.235f * l0 + 0.765f * l1;
    const float lng_comb = fast_log(phi * (1.0f / 0.235f))
                         + 5.0f * q0 * fast_log(theta * __builtin_amdgcn_rcpf(phi))
                         + l0 - (phi * (1.0f / 0.235f)) * xl;
    out[e] = lng_resid + lng_comb;
  }
}

extern "C" void kernel_launch(void* const* d_in, const int* in_sizes, int n_in,
                              void* d_out, int out_size, void* d_ws, size_t ws_size,
                              hipStream_t stream) {
  const float* my  = (const float*)d_in[0];
  const float* vc  = (const float*)d_in[1];
  const float* vts = (const float*)d_in[2];
  const float* vvt = (const float*)d_in[3];
  float* out = (float*)d_out;
  const int B = in_sizes[1];                    // v_compound is [B]
  const int grid = (B + 63) / 64;               // 64 elements per 256-thread block
  cosmo_mfma<<<grid, 256, 0, stream>>>(my, vc, vts, vvt, out, B);
}